// Round 8
// baseline (72.143 us; speedup 1.0000x reference)
//
#include <hip/hip_runtime.h>
#include <float.h>

#define NPRED 8192
#define NGT   32768
#define BLK   256
#define P     8
#define NSEG  512
#define SEGLEN (NGT / NSEG)          // 64 gt points per segment
#define NCHUNK (NPRED / (BLK * P))   // 4 pred chunks of 2048
#define G      8                     // group size for min3 tree
#define NGRP   (SEGLEN / G)          // 8 groups
#define FBLK   256
#define NPB    (NPRED / FBLK)        // 32 finalize blocks

// ws layout:
//   [0, NGT*16)            float4 gt4[NGT] = (-2gx,-2gy,-2gz,g2)   512KB
//   [+NGT*16, +NPRED*8)    u64 res[NPRED]  packed (scorekey<<32|idx) 64KB
//   [.., +NPB*8)           u64 bsums[NPB]
//   [.., +4)               u32 counter

__global__ void prep_kernel(const float* __restrict__ gt, float4* __restrict__ gt4,
                            unsigned long long* __restrict__ res,
                            unsigned int* __restrict__ counter) {
    int j = blockIdx.x * blockDim.x + threadIdx.x;
    if (j < NGT) {
        float x = gt[j * 6 + 0], y = gt[j * 6 + 1], z = gt[j * 6 + 2];
        gt4[j] = make_float4(-2.0f * x, -2.0f * y, -2.0f * z, x * x + y * y + z * z);
    }
    if (j < NPRED) res[j] = 0xFFFFFFFFFFFFFFFFull;   // must re-init: poison can be < real keys
    if (j == 0) *counter = 0u;
}

__device__ __forceinline__ unsigned int fkey(float f) {
    unsigned int u = __float_as_uint(f);
    return u ^ (unsigned int)(((int)u >> 31) | 0x80000000);
}

__device__ __forceinline__ float score(const float4& g, float px, float py, float pz) {
    // fixed fma chain: bit-exact reproducible at rescan
    return fmaf(g.x, px, fmaf(g.y, py, fmaf(g.z, pz, g.w)));
}

__global__ __launch_bounds__(BLK, 8) void argmin_kernel(const float* __restrict__ pred,
                                                        const float4* __restrict__ gt4,
                                                        unsigned long long* __restrict__ res) {
    const int t = threadIdx.x;
    const int chunk = blockIdx.x;
    const int seg = blockIdx.y;
    const int j0 = seg * SEGLEN;

    float px[P], py[P], pz[P], best[P];
    int bg[P];
    const int pbase = chunk * (BLK * P) + t;
    #pragma unroll
    for (int k = 0; k < P; ++k) {
        const float* p = pred + (size_t)(pbase + k * BLK) * 6;
        px[k] = p[0]; py[k] = p[1]; pz[k] = p[2];
        best[k] = FLT_MAX; bg[k] = 0;
    }

    // gt points read at wave-uniform addresses -> s_load into SGPRs (free broadcast,
    // zero VGPR pressure, no LDS). 8 points = 128B = 2x s_load_dwordx16 per group.
    #pragma unroll 1
    for (int grp = 0; grp < NGRP; ++grp) {
        const int base = j0 + grp * G;
        float4 g0 = gt4[base + 0], g1 = gt4[base + 1];
        float4 g2 = gt4[base + 2], g3 = gt4[base + 3];
        float4 g4 = gt4[base + 4], g5 = gt4[base + 5];
        float4 g6 = gt4[base + 6], g7 = gt4[base + 7];
        #pragma unroll
        for (int k = 0; k < P; ++k) {
            float s0 = score(g0, px[k], py[k], pz[k]);
            float s1 = score(g1, px[k], py[k], pz[k]);
            float s2 = score(g2, px[k], py[k], pz[k]);
            float s3 = score(g3, px[k], py[k], pz[k]);
            float s4 = score(g4, px[k], py[k], pz[k]);
            float s5 = score(g5, px[k], py[k], pz[k]);
            float s6 = score(g6, px[k], py[k], pz[k]);
            float s7 = score(g7, px[k], py[k], pz[k]);
            float t0 = fminf(fminf(s0, s1), s2);         // v_min3
            float t1 = fminf(fminf(s3, s4), s5);         // v_min3
            float t2 = fminf(fminf(s6, s7), t0);         // v_min3
            float m  = fminf(t1, t2);
            if (m < best[k]) { best[k] = m; bg[k] = grp; }  // strict <: earliest group wins
        }
    }

    // rescan winning group via per-lane global loads (L2-hot, 1KB window):
    // identical fma chain on identical data -> bit-exact equality
    #pragma unroll
    for (int k = 0; k < P; ++k) {
        const int gb = j0 + bg[k] * G;
        float s[G];
        #pragma unroll
        for (int o = 0; o < G; ++o)
            s[o] = score(gt4[gb + o], px[k], py[k], pz[k]);
        int off = G - 1;
        #pragma unroll
        for (int o = G - 2; o >= 0; --o)
            if (s[o] == best[k]) off = o;                // earliest match wins
        unsigned long long pk = ((unsigned long long)fkey(best[k]) << 32)
                              | (unsigned long long)(gb + off);
        // read-first filter: stale reads are >= committed value -> only extra atomics, never wrong
        unsigned long long cur = __hip_atomic_load(&res[pbase + k * BLK],
                                                   __ATOMIC_RELAXED, __HIP_MEMORY_SCOPE_AGENT);
        if (pk < cur) atomicMin(&res[pbase + k * BLK], pk);   // deterministic
    }
}

__global__ __launch_bounds__(FBLK) void finalize_kernel(const float* __restrict__ pred,
                                                        const float* __restrict__ gt,
                                                        const unsigned long long* __restrict__ res,
                                                        unsigned long long* __restrict__ bsums,
                                                        unsigned int* __restrict__ counter,
                                                        float* __restrict__ out) {
    int i = blockIdx.x * FBLK + threadIdx.x;
    int bidx = (int)(res[i] & 0xFFFFFFFFull);

    const float* g = &gt[(size_t)bidx * 6];
    float gx = g[0], gy = g[1], gz = g[2];
    float gnx = g[3], gny = g[4], gnz = g[5];
    const float* p = &pred[(size_t)i * 6];
    float px = p[0], py = p[1], pz = p[2];
    float pnx = p[3], pny = p[4], pnz = p[5];

    float dx = px - gx, dy = py - gy, dz = pz - gz;
    float v1 = dx * dx + dy * dy + dz * dz;

    float pn = sqrtf(pnx * pnx + pny * pny + pnz * pnz);
    float gn = sqrtf(gnx * gnx + gny * gny + gnz * gnz);
    float denom = fmaxf(pn, 1e-4f) * fmaxf(gn, 1e-4f);
    float cosv = (pnx * gnx + pny * gny + pnz * gnz) / denom;
    float v2 = 1.0f - cosv;

    #pragma unroll
    for (int off = 32; off > 0; off >>= 1) {
        v1 += __shfl_down(v1, off);
        v2 += __shfl_down(v2, off);
    }
    __shared__ float s1[FBLK / 64];
    __shared__ float s2[FBLK / 64];
    __shared__ int lastFlag;
    int wid = threadIdx.x >> 6;
    if ((threadIdx.x & 63) == 0) { s1[wid] = v1; s2[wid] = v2; }
    __syncthreads();
    if (threadIdx.x == 0) {
        float a = 0.0f, b = 0.0f;
        #pragma unroll
        for (int w = 0; w < FBLK / 64; ++w) { a += s1[w]; b += s2[w]; }
        unsigned long long pk = (unsigned long long)__float_as_uint(a)
                              | ((unsigned long long)__float_as_uint(b) << 32);
        __hip_atomic_store(&bsums[blockIdx.x], pk, __ATOMIC_RELEASE, __HIP_MEMORY_SCOPE_AGENT);
        unsigned int tk = __hip_atomic_fetch_add(counter, 1u, __ATOMIC_ACQ_REL, __HIP_MEMORY_SCOPE_AGENT);
        lastFlag = (tk == NPB - 1) ? 1 : 0;
    }
    __syncthreads();
    if (lastFlag && threadIdx.x < 64) {
        float a = 0.0f, b = 0.0f;
        if (threadIdx.x < NPB) {
            unsigned long long pk = __hip_atomic_load(&bsums[threadIdx.x],
                                                      __ATOMIC_ACQUIRE, __HIP_MEMORY_SCOPE_AGENT);
            a = __uint_as_float((unsigned int)(pk & 0xFFFFFFFFull));
            b = __uint_as_float((unsigned int)(pk >> 32));
        }
        #pragma unroll
        for (int off = 32; off > 0; off >>= 1) {
            a += __shfl_down(a, off);
            b += __shfl_down(b, off);
        }
        if (threadIdx.x == 0) out[0] = a / (NPRED * 3.0f) + b / (float)NPRED;
    }
}

extern "C" void kernel_launch(void* const* d_in, const int* in_sizes, int n_in,
                              void* d_out, int out_size, void* d_ws, size_t ws_size,
                              hipStream_t stream) {
    const float* pred_feat = (const float*)d_in[0];
    const float* gt_data   = (const float*)d_in[3];
    float* out = (float*)d_out;

    char* ws = (char*)d_ws;
    float4* gt4 = (float4*)ws;
    unsigned long long* res = (unsigned long long*)(ws + (size_t)NGT * 16);
    unsigned long long* bsums = (unsigned long long*)(ws + (size_t)NGT * 16 + (size_t)NPRED * 8);
    unsigned int* counter = (unsigned int*)(ws + (size_t)NGT * 16 + (size_t)NPRED * 8 + (size_t)NPB * 8);

    prep_kernel<<<NGT / 256, 256, 0, stream>>>(gt_data, gt4, res, counter);
    dim3 grid(NCHUNK, NSEG);
    argmin_kernel<<<grid, BLK, 0, stream>>>(pred_feat, gt4, res);
    finalize_kernel<<<NPB, FBLK, 0, stream>>>(pred_feat, gt_data, res, bsums, counter, out);
}

// Round 9
// 51.257 us; speedup vs baseline: 1.4075x; 1.4075x over previous
//
#include <hip/hip_runtime.h>
#include <float.h>

#define NPRED 8192
#define NGT   32768
#define BLK   256
#define P     8
#define NSEG  128
#define SEGLEN (NGT / NSEG)          // 256 gt points per segment (== BLK)
#define NCHUNK (NPRED / (BLK * P))   // 4 pred chunks of 2048 -> 512 blocks = 2/CU
#define G      8                     // group size for min3 tree
#define NGRP   (SEGLEN / G)          // 32 groups
#define FBLK   256
#define NPB    (NPRED / FBLK)        // 32 finalize blocks

// ws layout:
//   [0, NGT*16)            float4 gt4[NGT] = (-2gx,-2gy,-2gz,g2)   512KB
//   [+NGT*16, +NPRED*8)    u64 res[NPRED]  packed (scorekey<<32|idx) 64KB
//   [.., +NPB*8)           u64 bsums[NPB]
//   [.., +4)               u32 counter

__global__ void prep_kernel(const float* __restrict__ gt, float4* __restrict__ gt4,
                            unsigned long long* __restrict__ res,
                            unsigned int* __restrict__ counter) {
    int j = blockIdx.x * blockDim.x + threadIdx.x;
    if (j < NGT) {
        float x = gt[j * 6 + 0], y = gt[j * 6 + 1], z = gt[j * 6 + 2];
        gt4[j] = make_float4(-2.0f * x, -2.0f * y, -2.0f * z, x * x + y * y + z * z);
    }
    if (j < NPRED) res[j] = 0xFFFFFFFFFFFFFFFFull;   // must re-init: poison can be < real keys
    if (j == 0) *counter = 0u;
}

__device__ __forceinline__ unsigned int fkey(float f) {
    unsigned int u = __float_as_uint(f);
    return u ^ (unsigned int)(((int)u >> 31) | 0x80000000);
}

__device__ __forceinline__ float score(const float4& g, float px, float py, float pz) {
    // fixed fma chain: bit-exact reproducible at rescan (same input bits -> same result)
    return fmaf(g.x, px, fmaf(g.y, py, fmaf(g.z, pz, g.w)));
}

__global__ __launch_bounds__(BLK, 2) void argmin_kernel(const float* __restrict__ pred,
                                                        const float4* __restrict__ gt4,
                                                        unsigned long long* __restrict__ res) {
    __shared__ float4 tile[SEGLEN];              // 4KB; main-loop reads are wave-uniform -> broadcast
    const int t = threadIdx.x;
    const int chunk = blockIdx.x;
    const int seg = blockIdx.y;
    const int j0 = seg * SEGLEN;

    tile[t] = gt4[j0 + t];                       // SEGLEN == BLK, coalesced b128

    float px[P], py[P], pz[P], best[P];
    int bg[P];
    const int pbase = chunk * (BLK * P) + t;
    #pragma unroll
    for (int k = 0; k < P; ++k) {
        const float* p = pred + (size_t)(pbase + k * BLK) * 6;
        px[k] = p[0]; py[k] = p[1]; pz[k] = p[2];
        best[k] = FLT_MAX; bg[k] = 0;
    }
    __syncthreads();

    // unroll 1: keep exactly 8 float4 group values live (~32 VGPR) -> no allocator bailout
    #pragma unroll 1
    for (int grp = 0; grp < NGRP; ++grp) {
        const int base = grp * G;
        float4 g0 = tile[base + 0], g1 = tile[base + 1];
        float4 g2 = tile[base + 2], g3 = tile[base + 3];
        float4 g4 = tile[base + 4], g5 = tile[base + 5];
        float4 g6 = tile[base + 6], g7 = tile[base + 7];
        #pragma unroll
        for (int k = 0; k < P; ++k) {
            float s0 = score(g0, px[k], py[k], pz[k]);
            float s1 = score(g1, px[k], py[k], pz[k]);
            float s2 = score(g2, px[k], py[k], pz[k]);
            float s3 = score(g3, px[k], py[k], pz[k]);
            float s4 = score(g4, px[k], py[k], pz[k]);
            float s5 = score(g5, px[k], py[k], pz[k]);
            float s6 = score(g6, px[k], py[k], pz[k]);
            float s7 = score(g7, px[k], py[k], pz[k]);
            float t0 = fminf(fminf(s0, s1), s2);         // v_min3
            float t1 = fminf(fminf(s3, s4), s5);         // v_min3
            float t2 = fminf(fminf(s6, s7), t0);         // v_min3
            float m  = fminf(t1, t2);
            if (m < best[k]) { best[k] = m; bg[k] = grp; }  // strict <: earliest group wins
        }
    }

    // rescan winning group from GLOBAL gt4 (same buffer the tile was copied from ->
    // identical bits, identical fma chain -> bit-exact; per-lane loads, L2-hot, no LDS conflicts)
    #pragma unroll
    for (int k = 0; k < P; ++k) {
        const int gb = j0 + bg[k] * G;
        float s[G];
        #pragma unroll
        for (int o = 0; o < G; ++o)
            s[o] = score(gt4[gb + o], px[k], py[k], pz[k]);
        int off = G - 1;
        #pragma unroll
        for (int o = G - 2; o >= 0; --o)
            if (s[o] == best[k]) off = o;                // earliest match wins
        unsigned long long pk = ((unsigned long long)fkey(best[k]) << 32)
                              | (unsigned long long)(gb + off);
        // read-first filter: stale reads are >= committed value -> only extra atomics, never wrong
        unsigned long long cur = __hip_atomic_load(&res[pbase + k * BLK],
                                                   __ATOMIC_RELAXED, __HIP_MEMORY_SCOPE_AGENT);
        if (pk < cur) atomicMin(&res[pbase + k * BLK], pk);   // deterministic
    }
}

__global__ __launch_bounds__(FBLK) void finalize_kernel(const float* __restrict__ pred,
                                                        const float* __restrict__ gt,
                                                        const unsigned long long* __restrict__ res,
                                                        unsigned long long* __restrict__ bsums,
                                                        unsigned int* __restrict__ counter,
                                                        float* __restrict__ out) {
    int i = blockIdx.x * FBLK + threadIdx.x;
    int bidx = (int)(res[i] & 0xFFFFFFFFull);

    const float* g = &gt[(size_t)bidx * 6];
    float gx = g[0], gy = g[1], gz = g[2];
    float gnx = g[3], gny = g[4], gnz = g[5];
    const float* p = &pred[(size_t)i * 6];
    float px = p[0], py = p[1], pz = p[2];
    float pnx = p[3], pny = p[4], pnz = p[5];

    float dx = px - gx, dy = py - gy, dz = pz - gz;
    float v1 = dx * dx + dy * dy + dz * dz;

    float pn = sqrtf(pnx * pnx + pny * pny + pnz * pnz);
    float gn = sqrtf(gnx * gnx + gny * gny + gnz * gnz);
    float denom = fmaxf(pn, 1e-4f) * fmaxf(gn, 1e-4f);
    float cosv = (pnx * gnx + pny * gny + pnz * gnz) / denom;
    float v2 = 1.0f - cosv;

    #pragma unroll
    for (int off = 32; off > 0; off >>= 1) {
        v1 += __shfl_down(v1, off);
        v2 += __shfl_down(v2, off);
    }
    __shared__ float s1[FBLK / 64];
    __shared__ float s2[FBLK / 64];
    __shared__ int lastFlag;
    int wid = threadIdx.x >> 6;
    if ((threadIdx.x & 63) == 0) { s1[wid] = v1; s2[wid] = v2; }
    __syncthreads();
    if (threadIdx.x == 0) {
        float a = 0.0f, b = 0.0f;
        #pragma unroll
        for (int w = 0; w < FBLK / 64; ++w) { a += s1[w]; b += s2[w]; }
        unsigned long long pk = (unsigned long long)__float_as_uint(a)
                              | ((unsigned long long)__float_as_uint(b) << 32);
        __hip_atomic_store(&bsums[blockIdx.x], pk, __ATOMIC_RELEASE, __HIP_MEMORY_SCOPE_AGENT);
        unsigned int tk = __hip_atomic_fetch_add(counter, 1u, __ATOMIC_ACQ_REL, __HIP_MEMORY_SCOPE_AGENT);
        lastFlag = (tk == NPB - 1) ? 1 : 0;
    }
    __syncthreads();
    if (lastFlag && threadIdx.x < 64) {
        float a = 0.0f, b = 0.0f;
        if (threadIdx.x < NPB) {
            unsigned long long pk = __hip_atomic_load(&bsums[threadIdx.x],
                                                      __ATOMIC_ACQUIRE, __HIP_MEMORY_SCOPE_AGENT);
            a = __uint_as_float((unsigned int)(pk & 0xFFFFFFFFull));
            b = __uint_as_float((unsigned int)(pk >> 32));
        }
        #pragma unroll
        for (int off = 32; off > 0; off >>= 1) {
            a += __shfl_down(a, off);
            b += __shfl_down(b, off);
        }
        if (threadIdx.x == 0) out[0] = a / (NPRED * 3.0f) + b / (float)NPRED;
    }
}

extern "C" void kernel_launch(void* const* d_in, const int* in_sizes, int n_in,
                              void* d_out, int out_size, void* d_ws, size_t ws_size,
                              hipStream_t stream) {
    const float* pred_feat = (const float*)d_in[0];
    const float* gt_data   = (const float*)d_in[3];
    float* out = (float*)d_out;

    char* ws = (char*)d_ws;
    float4* gt4 = (float4*)ws;
    unsigned long long* res = (unsigned long long*)(ws + (size_t)NGT * 16);
    unsigned long long* bsums = (unsigned long long*)(ws + (size_t)NGT * 16 + (size_t)NPRED * 8);
    unsigned int* counter = (unsigned int*)(ws + (size_t)NGT * 16 + (size_t)NPRED * 8 + (size_t)NPB * 8);

    prep_kernel<<<NGT / 256, 256, 0, stream>>>(gt_data, gt4, res, counter);
    dim3 grid(NCHUNK, NSEG);
    argmin_kernel<<<grid, BLK, 0, stream>>>(pred_feat, gt4, res);
    finalize_kernel<<<NPB, FBLK, 0, stream>>>(pred_feat, gt_data, res, bsums, counter, out);
}